// Round 4
// baseline (115.769 us; speedup 1.0000x reference)
//
#include <hip/hip_runtime.h>
#include <math.h>

// Match numpy's unfused f32 arithmetic (fma contraction shifts IoU at the
// 0.45 decision boundary). R1-R11 with this pragma matched absmax 0.0.
#pragma clang fp contract(off)

#define PNUM    3000
#define NCLS    21
#define TOPK    200
#define BLOCK   1024
#define CHUNK   1024
#define NMS_T   0.45f
#define LO_BITS 0x3C23D70Bu          // smallest float bits strictly > 0.01f
#define HI_BITS 0x3F800001u          // > bits of any score in [0,1]
#define MAXKEEP (TOPK + 64)

// Refill ladder (R12 form — R13's count-aware refill measured as a
// regression and is reverted). Boundaries only affect performance.
__device__ __constant__ unsigned LADDER[15] = {
    0x3F333333u, 0x3F266666u, 0x3F19999Au, 0x3F0CCCCDu, 0x3F000000u,
    0x3EE66666u, 0x3ECCCCCDu, 0x3EB33333u, 0x3E99999Au, 0x3E800000u,
    0x3E4CCCCDu, 0x3E19999Au, 0x3DCCCCCDu, 0x3D4CCCCDu, LO_BITS };

__device__ __forceinline__ float iou_f(float4 a, float aa, float4 b, float ab) {
    float ltx = fmaxf(a.x, b.x);
    float lty = fmaxf(a.y, b.y);
    float rbx = fminf(a.z, b.z);
    float rby = fminf(a.w, b.w);
    float iw  = fmaxf(rbx - ltx, 0.0f);
    float ih  = fmaxf(rby - lty, 0.0f);
    float inter = iw * ih;
    float uni   = aa + ab - inter;           // keeper area first (ref order)
    return inter / fmaxf(uni, 1e-12f);
}

// R14 = R12 + live-list filter/compact. Old rounds re-checked every
// 64-candidate window against ALL committed keeps (CK phase), so dead
// candidates occupied round slots: round count = consumed/64 (~47). Now a
// compacted live-index list (ping-pong in the post-sort-free s_bufA/B) is
// filtered 1024-wide against only NEW keeps after each round; rounds take
// the first 64 LIVE candidates and need only the in-batch triangle + peel
// resolve. Exact: committed keeps are final, so filtering is sound;
// compaction preserves score order; triangle+peel is exact greedy on a
// fully-prefiltered batch -> identical keep sequence (absmax 0.0).
__global__ __launch_bounds__(BLOCK) void ssd_nms_kernel(
    const float* __restrict__ loc,     // [B, PNUM, 4]
    const float* __restrict__ conf,    // [B, PNUM, NCLS]
    const float* __restrict__ priors,  // [PNUM, 4]
    float* __restrict__ out)           // [B, NCLS, TOPK, 5]
{
    const int c   = blockIdx.x;
    const int b   = blockIdx.y;
    const int tid = threadIdx.x;

    float* outbase = out + ((size_t)(b * NCLS + c)) * (TOPK * 5);

    if (c == 0) {
        for (int i = tid; i < TOPK * 5; i += BLOCK) outbase[i] = 0.0f;
        return;
    }

    __shared__ unsigned long long s_bufA[CHUNK];  // 8 KB  sort ping / live idx
    __shared__ unsigned long long s_bufB[CHUNK];  // 8 KB  sort pong / live idx
    __shared__ float4             s_box[CHUNK];   // 16 KB decoded chunk boxes
    __shared__ float              s_area[CHUNK];  // 4 KB
    __shared__ float              s_score[CHUNK]; // 4 KB
    __shared__ float4             s_kb[MAXKEEP];  // committed keep boxes
    __shared__ float              s_ka[MAXKEEP];
    __shared__ unsigned long long s_supp[64];     // in-batch suppression bits
    __shared__ int                s_wcnt[16];     // per-wave counts
    __shared__ int s_m, s_cnt, s_done;

    const int lane = tid & 63;
    const int wav  = tid >> 6;

    // ---- per-thread score bits in registers (elements tid + q*1024) ----
    unsigned hb[4];
    const float* confb = conf + ((size_t)b * PNUM) * NCLS + c;
    #pragma unroll
    for (int q = 0; q < 4; ++q) {
        int i = tid + (q << 10);
        unsigned h = 0u;
        if (i < PNUM) {
            float s = confb[(size_t)i * NCLS];
            if (s > 0.01f) h = __float_as_uint(s);
        }
        hb[q] = h;
    }
    if (tid < 64) s_supp[lane] = 0ull;
    if (tid == 0) { s_cnt = 0; s_done = 0; }
    // (published by the first barrier below)

    unsigned Thi = HI_BITS;
    int rung = 0;
    bool done = false;

    for (;;) {   // ================= chunk loop =================
        unsigned T = LADDER[rung];

        // ---- optimistic compact of [T, Thi) (no count pass) ----
        __syncthreads();                 // protect s_bufA / s_m reuse
        if (tid == 0) s_m = 0;
        s_bufA[tid] = 0ull;              // pad keys sort last (desc)
        __syncthreads();
        #pragma unroll
        for (int q = 0; q < 4; ++q) {
            unsigned sb = hb[q];
            bool p = (sb >= T && sb < Thi);
            unsigned long long bal = __ballot(p);
            int wb = 0;
            if (lane == 0 && bal) wb = atomicAdd(&s_m, (int)__popcll(bal));
            wb = __shfl(wb, 0);
            if (p) {
                int dst = wb + (int)__popcll(bal & ((1ull << lane) - 1ull));
                if (dst < CHUNK) {
                    int i = tid + (q << 10);
                    s_bufA[dst] = ((unsigned long long)sb << 32) | (unsigned)(~i);
                }
            }
        }
        __syncthreads();
        int M = s_m;

        if (M > CHUNK) {
            // ---- rare fallback: bisect smallest T' in (T, Thi] with count
            //      <= CHUNK, then deterministic count+compact ----
            unsigned lo = T + 1, hi = Thi;
            while (lo < hi) {
                unsigned mid = lo + ((hi - lo) >> 1);
                __syncthreads();
                int c2 = 0;
                #pragma unroll
                for (int q = 0; q < 4; ++q)
                    c2 += (int)__popcll(__ballot(hb[q] >= mid && hb[q] < Thi));
                if (lane == 0) s_wcnt[wav] = c2;
                __syncthreads();
                int n = 0;
                #pragma unroll
                for (int w = 0; w < 16; ++w) n += s_wcnt[w];
                if (n <= CHUNK) hi = mid; else lo = mid + 1;
            }
            T = hi;
            // deterministic count + compact with final T
            __syncthreads();
            int wc = 0;
            #pragma unroll
            for (int q = 0; q < 4; ++q)
                wc += (int)__popcll(__ballot(hb[q] >= T && hb[q] < Thi));
            if (lane == 0) s_wcnt[wav] = wc;
            s_bufA[tid] = 0ull;
            __syncthreads();
            int wbase = 0; M = 0;
            #pragma unroll
            for (int w = 0; w < 16; ++w) {
                int v = s_wcnt[w];
                M += v;
                if (w < wav) wbase += v;
            }
            int base = wbase;
            #pragma unroll
            for (int q = 0; q < 4; ++q) {
                unsigned sb = hb[q];
                bool p = (sb >= T && sb < Thi);
                unsigned long long bal = __ballot(p);
                if (p) {
                    int dst = base + (int)__popcll(bal & ((1ull << lane) - 1ull));
                    int i = tid + (q << 10);
                    s_bufA[dst] = ((unsigned long long)sb << 32) | (unsigned)(~i);
                }
                base += (int)__popcll(bal);
            }
            __syncthreads();
        }

        if (M == 0) {
            if (T <= LO_BITS) break;       // nothing left at all
            Thi = T;
            while (rung < 14 && LADDER[rung] >= T) rung++;
            continue;
        }

        // ---- width-adaptive register bitonic sort, descending ----
        unsigned N = 64;
        while (N < (unsigned)M) N <<= 1;
        unsigned long long key = s_bufA[tid];
        int parity = 0;
        for (unsigned k = 2; k <= N; k <<= 1) {
            for (unsigned j = k >> 1; j > 0; j >>= 1) {
                unsigned long long pk;
                if (j >= 64) {
                    unsigned long long* buf = parity ? s_bufB : s_bufA;
                    buf[tid] = key;
                    __syncthreads();
                    pk = buf[tid ^ j];
                    parity ^= 1;
                } else {
                    pk = __shfl_xor(key, (int)j, 64);
                }
                bool takeMax  = (((tid & j) == 0) == ((tid & k) == 0));
                bool pGreater = pk > key;
                if (takeMax == pGreater) key = pk;
            }
        }

        // ---- decode chunk boxes (thread tid == sorted rank tid) ----
        if (key != 0ull) {
            unsigned idx = ~(unsigned)key;        // original prior index
            float4 l  = ((const float4*)loc)[(size_t)b * PNUM + idx];
            float4 pr = ((const float4*)priors)[idx];
            float cx = pr.x + l.x * 0.1f * pr.z;
            float cy = pr.y + l.y * 0.1f * pr.w;
            float w  = pr.z * expf(l.z * 0.2f);
            float h  = pr.w * expf(l.w * 0.2f);
            float x1 = cx - 0.5f * w;
            float y1 = cy - 0.5f * h;
            float x2 = x1 + w;
            float y2 = y1 + h;
            s_box[tid]   = make_float4(x1, y1, x2, y2);
            s_area[tid]  = (x2 - x1) * (y2 - y1);
            s_score[tid] = __uint_as_float((unsigned)(key >> 32));
        }
        // live-index list init (s_bufA/B are free after the sort: key is in
        // a register). uint view uses only the first 4 KB of each.
        unsigned* ibuf = reinterpret_cast<unsigned*>(s_bufA);
        unsigned* obuf = reinterpret_cast<unsigned*>(s_bufB);
        if (tid < M) ibuf[tid] = (unsigned)tid;
        __syncthreads();

        // ---- filter/round loop over the live list ----
        int live = M;
        int nf   = 0;     // keeps already applied to the live list
        int drop = 0;     // consumed head entries awaiting removal
        for (;;) {
            int cnt = s_cnt;                   // published at last barrier
            if (cnt > nf || drop > 0) {
                // filter survivors [drop, live) against keeps [nf, cnt),
                // compact into obuf (order-preserving)
                unsigned ci = 0u; bool alive = false;
                if (tid >= drop && tid < live) {
                    ci = ibuf[tid];
                    float4 bL = s_box[ci];
                    float  aL = s_area[ci];
                    alive = true;
                    for (int K = nf; K < cnt; ++K)
                        alive = alive && !(iou_f(s_kb[K], s_ka[K], bL, aL) > NMS_T);
                }
                unsigned long long bal = __ballot(alive);
                if (lane == 0) s_wcnt[wav] = (int)__popcll(bal);
                __syncthreads();
                int base = 0, tot = 0;
                #pragma unroll
                for (int w = 0; w < 16; ++w) {
                    int v = s_wcnt[w];
                    tot += v;
                    if (w < wav) base += v;
                }
                if (alive)
                    obuf[base + (int)__popcll(bal & ((1ull << lane) - 1ull))] = ci;
                unsigned* tsw = ibuf; ibuf = obuf; obuf = tsw;
                live = tot; nf = cnt; drop = 0;
                __syncthreads();
            }
            if (live == 0) break;

            int bn = live < 64 ? live : 64;

            // in-batch triangle only (batch is alive w.r.t. all committed
            // keeps by construction). 16 waves, 4 suppressor rows each.
            if (lane < bn) {
                unsigned ciL = ibuf[lane];
                float4 bL = s_box[ciL];
                float  aL = s_area[ciL];
                unsigned long long bits = 0ull;
                int M0 = wav << 2;
                #pragma unroll
                for (int q2 = 0; q2 < 4; ++q2) {
                    int Mi = M0 + q2;
                    if (Mi < lane) {
                        unsigned cj = ibuf[Mi];
                        if (iou_f(s_box[cj], s_area[cj], bL, aL) > NMS_T)
                            bits |= (1ull << Mi);
                    }
                }
                if (bits) atomicOr(&s_supp[lane], bits);
            }
            __syncthreads();

            // wave0 peel resolve (R12): keep min remaining, one ballot
            // removes all its victims.
            if (tid < 64) {
                unsigned long long own = s_supp[lane];
                bool aliv = (lane < bn);
                unsigned long long kept = __ballot(aliv && own == 0ull);
                unsigned long long rem0 = __ballot((own & kept) != 0ull);
                unsigned long long cand = __ballot(aliv && own != 0ull) & ~rem0;
                while (cand) {
                    int i = __ffsll(cand) - 1;    // min remaining: always kept
                    kept |= 1ull << i;
                    unsigned long long vic = __ballot(((own >> i) & 1ull) != 0ull);
                    cand &= ~vic;
                    cand &= ~(1ull << i);
                }
                int keptN = (int)__popcll(kept);
                bool me   = (kept >> lane) & 1ull;
                int krank = (int)__popcll(kept & ((1ull << lane) - 1ull));
                int cnt0  = s_cnt;
                if (me) {
                    int kid = cnt0 + krank;       // < MAXKEEP by construction
                    unsigned ciL = ibuf[lane];
                    float4 bx = s_box[ciL];
                    s_kb[kid] = bx;
                    s_ka[kid] = s_area[ciL];
                    if (kid < TOPK) {
                        float* o = outbase + (size_t)kid * 5;
                        o[0] = s_score[ciL];
                        o[1] = bx.x; o[2] = bx.y; o[3] = bx.z; o[4] = bx.w;
                    }
                }
                s_supp[lane] = 0ull;              // reset for next round
                if (lane == 0) {
                    s_cnt  = cnt0 + keptN;
                    s_done = (cnt0 + keptN >= TOPK) ? 1 : 0;
                }
            }
            __syncthreads();
            if (s_done) { done = true; break; }   // first TOPK rows fixed
            drop = bn;                            // consumed; removed next filter
        }

        if (done) break;
        if (T <= LO_BITS) break;                  // all candidates consumed
        Thi = T;                                  // next rung: scores in [?, T)
        while (rung < 14 && LADDER[rung] >= T) rung++;
    }

    // ---- zero unwritten tail rows ----
    const int cf = s_cnt < TOPK ? s_cnt : TOPK;
    for (int r = cf + tid; r < TOPK; r += BLOCK) {
        float* o = outbase + (size_t)r * 5;
        o[0] = 0.f; o[1] = 0.f; o[2] = 0.f; o[3] = 0.f; o[4] = 0.f;
    }
}

extern "C" void kernel_launch(void* const* d_in, const int* in_sizes, int n_in,
                              void* d_out, int out_size, void* d_ws, size_t ws_size,
                              hipStream_t stream) {
    const float* loc    = (const float*)d_in[0];
    const float* conf   = (const float*)d_in[1];
    const float* priors = (const float*)d_in[2];
    float* out          = (float*)d_out;
    const int B = in_sizes[0] / (PNUM * 4);   // 8
    dim3 grid(NCLS, B);
    ssd_nms_kernel<<<grid, BLOCK, 0, stream>>>(loc, conf, priors, out);
}

// Round 6
// 90.176 us; speedup vs baseline: 1.2838x; 1.2838x over previous
//
#include <hip/hip_runtime.h>
#include <math.h>

// Match numpy's unfused f32 arithmetic (fma contraction shifts IoU at the
// 0.45 decision boundary). R1-R11 with this pragma matched absmax 0.0.
#pragma clang fp contract(off)

#define PNUM    3000
#define NCLS    21
#define TOPK    200
#define BLOCK   1024
#define CHUNK   1024
#define NMS_T   0.45f
#define LO_BITS 0x3C23D70Bu          // smallest float bits strictly > 0.01f
#define HI_BITS 0x3F800001u          // > bits of any score in [0,1]
#define MAXKEEP (TOPK + 64)

// Refill ladder: rung 0 = [0.70, 1.0), then 0.05-wide rungs down to 0.05,
// final rung ends at LO_BITS. Boundaries only affect performance, not
// correctness (each rung is fully sorted; rungs descend by score).
__device__ __constant__ unsigned LADDER[15] = {
    0x3F333333u, 0x3F266666u, 0x3F19999Au, 0x3F0CCCCDu, 0x3F000000u,
    0x3EE66666u, 0x3ECCCCCDu, 0x3EB33333u, 0x3E99999Au, 0x3E800000u,
    0x3E4CCCCDu, 0x3E19999Au, 0x3DCCCCCDu, 0x3D4CCCCDu, LO_BITS };

__device__ __forceinline__ float iou_f(float4 a, float aa, float4 b, float ab) {
    float ltx = fmaxf(a.x, b.x);
    float lty = fmaxf(a.y, b.y);
    float rbx = fminf(a.z, b.z);
    float rby = fminf(a.w, b.w);
    float iw  = fmaxf(rbx - ltx, 0.0f);
    float ih  = fmaxf(rby - lty, 0.0f);
    float inter = iw * ih;
    float uni   = aa + ab - inter;           // keeper area first (ref order)
    return inter / fmaxf(uni, 1e-12f);
}

// R15 = R12 (peeling resolve; best, 90.0us harness) + ONE prefilter per
// refill chunk. R14's per-round filter regressed (4 barriers/round +
// scattered LDS > CK savings; kernel 61us, VALUBusy 33% = serialization-
// bound). Here chunks entered with base0>0 committed keeps are filtered
// ONCE, 1024-wide, against those keeps (early-exit serial loop/thread),
// survivors physically compacted in s_box/s_area/s_score (order-preserving,
// 2 barriers total). Rounds are the UNCHANGED R12 machinery on survivors;
// CK stripes only keeps committed within this chunk (K = base0+wav). Chunk 1
// is bit-identical to R12. Exact: committed keeps are final -> filtering
// sound; order preserved -> same greedy sequence -> absmax 0.0.
__global__ __launch_bounds__(BLOCK) void ssd_nms_kernel(
    const float* __restrict__ loc,     // [B, PNUM, 4]
    const float* __restrict__ conf,    // [B, PNUM, NCLS]
    const float* __restrict__ priors,  // [PNUM, 4]
    float* __restrict__ out)           // [B, NCLS, TOPK, 5]
{
    const int c   = blockIdx.x;
    const int b   = blockIdx.y;
    const int tid = threadIdx.x;

    float* outbase = out + ((size_t)(b * NCLS + c)) * (TOPK * 5);

    if (c == 0) {
        for (int i = tid; i < TOPK * 5; i += BLOCK) outbase[i] = 0.0f;
        return;
    }

    __shared__ unsigned long long s_bufA[CHUNK];  // 8 KB  sort ping
    __shared__ unsigned long long s_bufB[CHUNK];  // 8 KB  sort pong
    __shared__ float4             s_box[CHUNK];   // 16 KB decoded chunk boxes
    __shared__ float              s_area[CHUNK];  // 4 KB
    __shared__ float              s_score[CHUNK]; // 4 KB
    __shared__ float4             s_kb[MAXKEEP];  // committed keep boxes
    __shared__ float              s_ka[MAXKEEP];
    __shared__ unsigned long long s_supp[64];     // in-batch suppression bits
    __shared__ int                s_supc[64];     // suppressed-by-committed flag
    __shared__ int                s_wcnt[16];     // per-wave counts
    __shared__ int s_m, s_cnt, s_done;

    const int lane = tid & 63;
    const int wav  = tid >> 6;

    // ---- per-thread score bits in registers (elements tid + q*1024) ----
    unsigned hb[4];
    const float* confb = conf + ((size_t)b * PNUM) * NCLS + c;
    #pragma unroll
    for (int q = 0; q < 4; ++q) {
        int i = tid + (q << 10);
        unsigned h = 0u;
        if (i < PNUM) {
            float s = confb[(size_t)i * NCLS];
            if (s > 0.01f) h = __float_as_uint(s);
        }
        hb[q] = h;
    }
    if (tid < 64) { s_supp[lane] = 0ull; s_supc[lane] = 0; }
    if (tid == 0) { s_cnt = 0; s_done = 0; }
    // (published by the first barrier below)

    unsigned Thi = HI_BITS;
    int rung = 0;
    bool done = false;

    for (;;) {   // ================= chunk loop =================
        unsigned T = LADDER[rung];

        // ---- optimistic compact of [T, Thi) (no count pass) ----
        __syncthreads();                 // protect s_bufA / s_m reuse
        if (tid == 0) s_m = 0;
        s_bufA[tid] = 0ull;              // pad keys sort last (desc)
        __syncthreads();
        #pragma unroll
        for (int q = 0; q < 4; ++q) {
            unsigned sb = hb[q];
            bool p = (sb >= T && sb < Thi);
            unsigned long long bal = __ballot(p);
            int wb = 0;
            if (lane == 0 && bal) wb = atomicAdd(&s_m, (int)__popcll(bal));
            wb = __shfl(wb, 0);
            if (p) {
                int dst = wb + (int)__popcll(bal & ((1ull << lane) - 1ull));
                if (dst < CHUNK) {
                    int i = tid + (q << 10);
                    s_bufA[dst] = ((unsigned long long)sb << 32) | (unsigned)(~i);
                }
            }
        }
        __syncthreads();
        int M = s_m;
        const int base0 = s_cnt;         // keeps committed before this chunk

        if (M > CHUNK) {
            // ---- rare fallback: bisect smallest T' in (T, Thi] with count
            //      <= CHUNK, then deterministic count+compact ----
            unsigned lo = T + 1, hi = Thi;
            while (lo < hi) {
                unsigned mid = lo + ((hi - lo) >> 1);
                __syncthreads();
                int c2 = 0;
                #pragma unroll
                for (int q = 0; q < 4; ++q)
                    c2 += (int)__popcll(__ballot(hb[q] >= mid && hb[q] < Thi));
                if (lane == 0) s_wcnt[wav] = c2;
                __syncthreads();
                int n = 0;
                #pragma unroll
                for (int w = 0; w < 16; ++w) n += s_wcnt[w];
                if (n <= CHUNK) hi = mid; else lo = mid + 1;
            }
            T = hi;
            // deterministic count + compact with final T
            __syncthreads();
            int wc = 0;
            #pragma unroll
            for (int q = 0; q < 4; ++q)
                wc += (int)__popcll(__ballot(hb[q] >= T && hb[q] < Thi));
            if (lane == 0) s_wcnt[wav] = wc;
            s_bufA[tid] = 0ull;
            __syncthreads();
            int wbase = 0; M = 0;
            #pragma unroll
            for (int w = 0; w < 16; ++w) {
                int v = s_wcnt[w];
                M += v;
                if (w < wav) wbase += v;
            }
            int base = wbase;
            #pragma unroll
            for (int q = 0; q < 4; ++q) {
                unsigned sb = hb[q];
                bool p = (sb >= T && sb < Thi);
                unsigned long long bal = __ballot(p);
                if (p) {
                    int dst = base + (int)__popcll(bal & ((1ull << lane) - 1ull));
                    int i = tid + (q << 10);
                    s_bufA[dst] = ((unsigned long long)sb << 32) | (unsigned)(~i);
                }
                base += (int)__popcll(bal);
            }
            __syncthreads();
        }

        if (M == 0) {
            if (T <= LO_BITS) break;       // nothing left at all
            Thi = T;
            while (rung < 14 && LADDER[rung] >= T) rung++;
            continue;
        }

        // ---- width-adaptive register bitonic sort, descending ----
        // N = next pow2 >= M (>=64). Lanes >= N hold zero keys: harmless in
        // shfl stages (zeros swap with zeros) and LDS stages (read/write the
        // unused upper region). Barriers are uniform (N is block-uniform).
        unsigned N = 64;
        while (N < (unsigned)M) N <<= 1;
        unsigned long long key = s_bufA[tid];
        int parity = 0;
        for (unsigned k = 2; k <= N; k <<= 1) {
            for (unsigned j = k >> 1; j > 0; j >>= 1) {
                unsigned long long pk;
                if (j >= 64) {
                    unsigned long long* buf = parity ? s_bufB : s_bufA;
                    buf[tid] = key;
                    __syncthreads();
                    pk = buf[tid ^ j];
                    parity ^= 1;
                } else {
                    pk = __shfl_xor(key, (int)j, 64);
                }
                bool takeMax  = (((tid & j) == 0) == ((tid & k) == 0));
                bool pGreater = pk > key;
                if (takeMax == pGreater) key = pk;
            }
        }

        // ---- decode chunk boxes (thread tid == sorted rank tid) ----
        if (key != 0ull) {
            unsigned idx = ~(unsigned)key;        // original prior index
            float4 l  = ((const float4*)loc)[(size_t)b * PNUM + idx];
            float4 pr = ((const float4*)priors)[idx];
            float cx = pr.x + l.x * 0.1f * pr.z;
            float cy = pr.y + l.y * 0.1f * pr.w;
            float w  = pr.z * expf(l.z * 0.2f);
            float h  = pr.w * expf(l.w * 0.2f);
            float x1 = cx - 0.5f * w;
            float y1 = cy - 0.5f * h;
            float x2 = x1 + w;
            float y2 = y1 + h;
            s_box[tid]   = make_float4(x1, y1, x2, y2);
            s_area[tid]  = (x2 - x1) * (y2 - y1);
            s_score[tid] = __uint_as_float((unsigned)(key >> 32));
        }
        __syncthreads();

        // ---- per-chunk prefilter vs pre-chunk committed keeps ----
        int Mlive = M;
        if (base0 > 0) {
            float4 bx = make_float4(0.f, 0.f, 0.f, 0.f);
            float  ar = 0.f, sc = 0.f;
            bool alive = false;
            if (tid < M) {
                bx = s_box[tid]; ar = s_area[tid]; sc = s_score[tid];
                alive = true;
                for (int K = 0; K < base0; ++K) {
                    if (iou_f(s_kb[K], s_ka[K], bx, ar) > NMS_T) { alive = false; break; }
                }
            }
            unsigned long long bal = __ballot(alive);
            if (lane == 0) s_wcnt[wav] = (int)__popcll(bal);
            __syncthreads();              // all reads done before writes below
            int basew = 0, tot = 0;
            #pragma unroll
            for (int w = 0; w < 16; ++w) {
                int v = s_wcnt[w];
                tot += v;
                if (w < wav) basew += v;
            }
            if (alive) {
                int dst = basew + (int)__popcll(bal & ((1ull << lane) - 1ull));
                s_box[dst] = bx; s_area[dst] = ar; s_score[dst] = sc;
            }
            Mlive = tot;
            __syncthreads();
        }
        if (Mlive == 0) {
            if (T <= LO_BITS) break;
            Thi = T;
            while (rung < 14 && LADDER[rung] >= T) rung++;
            continue;
        }

        // ---- lazy greedy rounds: 64 sorted positions per round ----
        int pos = 0;
        while (pos < Mlive) {
            int bn  = Mlive - pos; if (bn > 64) bn = 64;
            int cnt = s_cnt;                      // published at last barrier

            // CK: all 16 waves check candidates vs keeps committed WITHIN
            // this chunk (pre-chunk keeps handled by the prefilter) +
            // in-batch triangle. Branchless over keeps: LDS loads pipeline.
            if (lane < bn) {
                float4 bL = s_box[pos + lane];
                float  aL = s_area[pos + lane];
                bool bad = false;
                #pragma unroll 2
                for (int K = base0 + wav; K < cnt; K += 16)
                    bad |= (iou_f(s_kb[K], s_ka[K], bL, aL) > NMS_T);
                if (bad) s_supc[lane] = 1;        // all writers store 1: race-safe
                unsigned long long bits = 0ull;
                int M0 = wav << 2;
                #pragma unroll
                for (int q2 = 0; q2 < 4; ++q2) {
                    int Mi = M0 + q2;
                    if (Mi < lane) {
                        if (iou_f(s_box[pos + Mi], s_area[pos + Mi], bL, aL) > NMS_T)
                            bits |= (1ull << Mi);
                    }
                }
                if (bits) atomicOr(&s_supp[lane], bits);
            }
            __syncthreads();

            // D: wave0 resolves greedy recurrence by PEELING: keep the
            // minimum remaining candidate, remove all its victims with ONE
            // ballot of (own>>i)&1. Iterations = in-batch keeps.
            if (tid < 64) {
                unsigned long long own      = s_supp[lane];
                unsigned long long deadmask = __ballot(s_supc[lane] != 0);
                bool alive = (lane < bn) && !((deadmask >> lane) & 1ull);
                // lanes with no in-batch suppressors are kept immediately
                unsigned long long kept = __ballot(alive && own == 0ull);
                // one ballot removes every lane suppressed by an auto-kept lane
                unsigned long long rem0 = __ballot((own & kept) != 0ull);
                unsigned long long cand = __ballot(alive && own != 0ull) & ~rem0;
                while (cand) {
                    int i = __ffsll(cand) - 1;    // min remaining: always kept
                    kept |= 1ull << i;
                    unsigned long long vic = __ballot(((own >> i) & 1ull) != 0ull);
                    cand &= ~vic;
                    cand &= ~(1ull << i);
                }
                int keptN = (int)__popcll(kept);
                bool me   = (kept >> lane) & 1ull;
                int krank = (int)__popcll(kept & ((1ull << lane) - 1ull));
                if (me) {
                    int kid = cnt + krank;        // < MAXKEEP by construction
                    float4 bx = s_box[pos + lane];
                    s_kb[kid] = bx;
                    s_ka[kid] = s_area[pos + lane];
                    if (kid < TOPK) {
                        float* o = outbase + (size_t)kid * 5;
                        o[0] = s_score[pos + lane];
                        o[1] = bx.x; o[2] = bx.y; o[3] = bx.z; o[4] = bx.w;
                    }
                }
                s_supp[lane] = 0ull;              // reset for next round
                s_supc[lane] = 0;
                if (lane == 0) {
                    s_cnt  = cnt + keptN;
                    s_done = (cnt + keptN >= TOPK) ? 1 : 0;
                }
            }
            __syncthreads();
            if (s_done) { done = true; break; }   // first TOPK rows fixed
            pos += bn;
        }

        if (done) break;
        if (T <= LO_BITS) break;                  // all candidates consumed
        Thi = T;                                  // next rung: scores in [?, T)
        // advance rung index past any boundary == T (bisect may have raised T)
        while (rung < 14 && LADDER[rung] >= T) rung++;
    }

    // ---- zero unwritten tail rows ----
    const int cf = s_cnt < TOPK ? s_cnt : TOPK;
    for (int r = cf + tid; r < TOPK; r += BLOCK) {
        float* o = outbase + (size_t)r * 5;
        o[0] = 0.f; o[1] = 0.f; o[2] = 0.f; o[3] = 0.f; o[4] = 0.f;
    }
}

extern "C" void kernel_launch(void* const* d_in, const int* in_sizes, int n_in,
                              void* d_out, int out_size, void* d_ws, size_t ws_size,
                              hipStream_t stream) {
    const float* loc    = (const float*)d_in[0];
    const float* conf   = (const float*)d_in[1];
    const float* priors = (const float*)d_in[2];
    float* out          = (float*)d_out;
    const int B = in_sizes[0] / (PNUM * 4);   // 8
    dim3 grid(NCLS, B);
    ssd_nms_kernel<<<grid, BLOCK, 0, stream>>>(loc, conf, priors, out);
}

// Round 9
// 90.031 us; speedup vs baseline: 1.2859x; 1.0016x over previous
//
#include <hip/hip_runtime.h>
#include <math.h>

// Match numpy's unfused f32 arithmetic (fma contraction shifts IoU at the
// 0.45 decision boundary). R1-R11 with this pragma matched absmax 0.0.
#pragma clang fp contract(off)

#define PNUM    3000
#define NCLS    21
#define TOPK    200
#define BLOCK   1024
#define CHUNK   1024
#define NMS_T   0.45f
#define LO_BITS 0x3C23D70Bu          // smallest float bits strictly > 0.01f
#define HI_BITS 0x3F800001u          // > bits of any score in [0,1]
#define MAXKEEP (TOPK + 64)

// Refill ladder: rung 0 = [0.70, 1.0), then 0.05-wide rungs down to 0.05,
// final rung ends at LO_BITS. Boundaries only affect performance, not
// correctness (each rung is fully sorted; rungs descend by score).
__device__ __constant__ unsigned LADDER[15] = {
    0x3F333333u, 0x3F266666u, 0x3F19999Au, 0x3F0CCCCDu, 0x3F000000u,
    0x3EE66666u, 0x3ECCCCCDu, 0x3EB33333u, 0x3E99999Au, 0x3E800000u,
    0x3E4CCCCDu, 0x3E19999Au, 0x3DCCCCCDu, 0x3D4CCCCDu, LO_BITS };

__device__ __forceinline__ float iou_f(float4 a, float aa, float4 b, float ab) {
    float ltx = fmaxf(a.x, b.x);
    float lty = fmaxf(a.y, b.y);
    float rbx = fminf(a.z, b.z);
    float rby = fminf(a.w, b.w);
    float iw  = fmaxf(rbx - ltx, 0.0f);
    float ih  = fmaxf(rby - lty, 0.0f);
    float inter = iw * ih;
    float uni   = aa + ab - inter;           // keeper area first (ref order)
    return inter / fmaxf(uni, 1e-12f);
}

// R16 = R15 + refill-pipeline cuts (R15 measured neutral: blocks mostly
// finish in chunk 1, so rounds ~14 and the refill pipeline is the largest
// attackable cost). (1) ALL 3000 boxes pre-decoded once into LDS via
// coalesced float4 loads — per-chunk scattered loc/priors decode removed;
// chunks carry only 8B keys, rounds index s_allbox[idx]. (2) Bitonic LDS
// stage pairs (j, j/2 both >=64) fused into ONE write+barrier+3 reads
// (directions depend only on tid bits; (tid^j2)&{k,j} == tid&{k,j} since
// k,j,j2 are distinct bits) — 10 -> 6 barrier passes per 1024-sort.
// Comparator and network identical -> same sorted order -> bit-exact.
__global__ __launch_bounds__(BLOCK) void ssd_nms_kernel(
    const float* __restrict__ loc,     // [B, PNUM, 4]
    const float* __restrict__ conf,    // [B, PNUM, NCLS]
    const float* __restrict__ priors,  // [PNUM, 4]
    float* __restrict__ out)           // [B, NCLS, TOPK, 5]
{
    const int c   = blockIdx.x;
    const int b   = blockIdx.y;
    const int tid = threadIdx.x;

    float* outbase = out + ((size_t)(b * NCLS + c)) * (TOPK * 5);

    if (c == 0) {
        for (int i = tid; i < TOPK * 5; i += BLOCK) outbase[i] = 0.0f;
        return;
    }

    __shared__ unsigned long long s_bufA[CHUNK];   // 8 KB  sort ping / keys
    __shared__ unsigned long long s_bufB[CHUNK];   // 8 KB  sort pong / keys
    __shared__ float4             s_allbox[PNUM];  // 48 KB all decoded boxes
    __shared__ float              s_allarea[PNUM]; // 12 KB
    __shared__ float4             s_kb[MAXKEEP];   // committed keep boxes
    __shared__ float              s_ka[MAXKEEP];
    __shared__ unsigned long long s_supp[64];      // in-batch suppression bits
    __shared__ int                s_supc[64];      // suppressed-by-committed
    __shared__ int                s_wcnt[16];      // per-wave counts
    __shared__ int s_m, s_cnt, s_done;

    const int lane = tid & 63;
    const int wav  = tid >> 6;

    // ---- per-thread score bits in registers (elements tid + q*1024) ----
    unsigned hb[4];
    const float* confb = conf + ((size_t)b * PNUM) * NCLS + c;
    #pragma unroll
    for (int q = 0; q < 4; ++q) {
        int i = tid + (q << 10);
        unsigned h = 0u;
        if (i < PNUM) {
            float s = confb[(size_t)i * NCLS];
            if (s > 0.01f) h = __float_as_uint(s);
        }
        hb[q] = h;
    }

    // ---- pre-decode ALL priors into LDS (coalesced, once per block) ----
    for (int i = tid; i < PNUM; i += BLOCK) {
        float4 l  = ((const float4*)loc)[(size_t)b * PNUM + i];
        float4 pr = ((const float4*)priors)[i];
        float cx = pr.x + l.x * 0.1f * pr.z;
        float cy = pr.y + l.y * 0.1f * pr.w;
        float w  = pr.z * expf(l.z * 0.2f);
        float h  = pr.w * expf(l.w * 0.2f);
        float x1 = cx - 0.5f * w;
        float y1 = cy - 0.5f * h;
        float x2 = x1 + w;
        float y2 = y1 + h;
        s_allbox[i]  = make_float4(x1, y1, x2, y2);
        s_allarea[i] = (x2 - x1) * (y2 - y1);
    }

    if (tid < 64) { s_supp[lane] = 0ull; s_supc[lane] = 0; }
    if (tid == 0) { s_cnt = 0; s_done = 0; }
    // (published by the first barrier below)

    unsigned Thi = HI_BITS;
    int rung = 0;
    bool done = false;

    for (;;) {   // ================= chunk loop =================
        unsigned T = LADDER[rung];

        // ---- optimistic compact of [T, Thi) (no count pass) ----
        __syncthreads();                 // protect s_bufA / s_m reuse
        if (tid == 0) s_m = 0;
        s_bufA[tid] = 0ull;              // pad keys sort last (desc)
        __syncthreads();
        #pragma unroll
        for (int q = 0; q < 4; ++q) {
            unsigned sb = hb[q];
            bool p = (sb >= T && sb < Thi);
            unsigned long long bal = __ballot(p);
            int wb = 0;
            if (lane == 0 && bal) wb = atomicAdd(&s_m, (int)__popcll(bal));
            wb = __shfl(wb, 0);
            if (p) {
                int dst = wb + (int)__popcll(bal & ((1ull << lane) - 1ull));
                if (dst < CHUNK) {
                    int i = tid + (q << 10);
                    s_bufA[dst] = ((unsigned long long)sb << 32) | (unsigned)(~i);
                }
            }
        }
        __syncthreads();
        int M = s_m;
        const int base0 = s_cnt;         // keeps committed before this chunk

        if (M > CHUNK) {
            // ---- rare fallback: bisect smallest T' in (T, Thi] with count
            //      <= CHUNK, then deterministic count+compact ----
            unsigned lo = T + 1, hi = Thi;
            while (lo < hi) {
                unsigned mid = lo + ((hi - lo) >> 1);
                __syncthreads();
                int c2 = 0;
                #pragma unroll
                for (int q = 0; q < 4; ++q)
                    c2 += (int)__popcll(__ballot(hb[q] >= mid && hb[q] < Thi));
                if (lane == 0) s_wcnt[wav] = c2;
                __syncthreads();
                int n = 0;
                #pragma unroll
                for (int w = 0; w < 16; ++w) n += s_wcnt[w];
                if (n <= CHUNK) hi = mid; else lo = mid + 1;
            }
            T = hi;
            // deterministic count + compact with final T
            __syncthreads();
            int wc = 0;
            #pragma unroll
            for (int q = 0; q < 4; ++q)
                wc += (int)__popcll(__ballot(hb[q] >= T && hb[q] < Thi));
            if (lane == 0) s_wcnt[wav] = wc;
            s_bufA[tid] = 0ull;
            __syncthreads();
            int wbase = 0; M = 0;
            #pragma unroll
            for (int w = 0; w < 16; ++w) {
                int v = s_wcnt[w];
                M += v;
                if (w < wav) wbase += v;
            }
            int base = wbase;
            #pragma unroll
            for (int q = 0; q < 4; ++q) {
                unsigned sb = hb[q];
                bool p = (sb >= T && sb < Thi);
                unsigned long long bal = __ballot(p);
                if (p) {
                    int dst = base + (int)__popcll(bal & ((1ull << lane) - 1ull));
                    int i = tid + (q << 10);
                    s_bufA[dst] = ((unsigned long long)sb << 32) | (unsigned)(~i);
                }
                base += (int)__popcll(bal);
            }
            __syncthreads();
        }

        if (M == 0) {
            if (T <= LO_BITS) break;       // nothing left at all
            Thi = T;
            while (rung < 14 && LADDER[rung] >= T) rung++;
            continue;
        }

        // ---- width-adaptive register bitonic sort, descending ----
        // N = next pow2 >= M (>=64). Lanes >= N hold zero keys: harmless.
        // LDS stage pairs (j, j/2 both >=64) fused: one write+barrier+3
        // reads computes both stages locally (see header comment).
        unsigned N = 64;
        while (N < (unsigned)M) N <<= 1;
        unsigned long long key = s_bufA[tid];
        int parity = 0;
        for (unsigned k = 2; k <= N; k <<= 1) {
            unsigned j = k >> 1;
            while (j >= 64) {
                unsigned long long* buf = parity ? s_bufB : s_bufA;
                unsigned j2 = j >> 1;
                buf[tid] = key;
                __syncthreads();
                if (j2 >= 64) {         // fused pair (j, j2)
                    unsigned long long a  = buf[tid ^ j];
                    unsigned long long b2 = buf[tid ^ j2];
                    unsigned long long c2 = buf[tid ^ (j | j2)];
                    bool up   = ((tid & k) == 0);
                    bool tmj  = ((tid & j)  == 0) == up;
                    unsigned long long m1 = (tmj  == (a  > key)) ? a  : key;
                    unsigned long long m2 = (tmj  == (c2 > b2 )) ? c2 : b2;
                    bool tmj2 = ((tid & j2) == 0) == up;
                    key = (tmj2 == (m2 > m1)) ? m2 : m1;
                    j >>= 2;
                } else {                // single LDS stage (j == 64)
                    unsigned long long pk = buf[tid ^ j];
                    bool tm = ((tid & j) == 0) == ((tid & k) == 0);
                    if (tm == (pk > key)) key = pk;
                    j >>= 1;
                }
                parity ^= 1;
            }
            for (; j > 0; j >>= 1) {
                unsigned long long pk = __shfl_xor(key, (int)j, 64);
                bool tm = ((tid & j) == 0) == ((tid & k) == 0);
                if (tm == (pk > key)) key = pk;
            }
        }

        // ---- stage sorted keys (rank tid) for cross-wave access ----
        __syncthreads();              // all sort reads done before re-staging
        s_bufA[tid] = key;
        __syncthreads();
        unsigned long long* keys = s_bufA;

        // ---- per-chunk prefilter vs pre-chunk committed keeps ----
        int Mlive = M;
        if (base0 > 0) {
            unsigned long long kk = 0ull;
            bool alive = false;
            if (tid < M) {
                kk = keys[tid];
                unsigned idx = ~(unsigned)kk;
                float4 bx = s_allbox[idx];
                float  ar = s_allarea[idx];
                alive = true;
                for (int K = 0; K < base0; ++K) {
                    if (iou_f(s_kb[K], s_ka[K], bx, ar) > NMS_T) { alive = false; break; }
                }
            }
            unsigned long long bal = __ballot(alive);
            if (lane == 0) s_wcnt[wav] = (int)__popcll(bal);
            __syncthreads();          // all key reads done before s_bufB write
            int basew = 0, tot = 0;
            #pragma unroll
            for (int w = 0; w < 16; ++w) {
                int v = s_wcnt[w];
                tot += v;
                if (w < wav) basew += v;
            }
            if (alive)
                s_bufB[basew + (int)__popcll(bal & ((1ull << lane) - 1ull))] = kk;
            Mlive = tot;
            keys = s_bufB;
            __syncthreads();
        }
        if (Mlive == 0) {
            if (T <= LO_BITS) break;
            Thi = T;
            while (rung < 14 && LADDER[rung] >= T) rung++;
            continue;
        }

        // ---- lazy greedy rounds: 64 sorted positions per round ----
        int pos = 0;
        while (pos < Mlive) {
            int bn  = Mlive - pos; if (bn > 64) bn = 64;
            int cnt = s_cnt;                      // published at last barrier

            // CK: all 16 waves check candidates vs keeps committed WITHIN
            // this chunk (pre-chunk keeps handled by the prefilter) +
            // in-batch triangle. Branchless over keeps: LDS loads pipeline.
            if (lane < bn) {
                unsigned idxL = ~(unsigned)keys[pos + lane];
                float4 bL = s_allbox[idxL];
                float  aL = s_allarea[idxL];
                bool bad = false;
                #pragma unroll 2
                for (int K = base0 + wav; K < cnt; K += 16)
                    bad |= (iou_f(s_kb[K], s_ka[K], bL, aL) > NMS_T);
                if (bad) s_supc[lane] = 1;        // all writers store 1: race-safe
                unsigned long long bits = 0ull;
                int M0 = wav << 2;
                #pragma unroll
                for (int q2 = 0; q2 < 4; ++q2) {
                    int Mi = M0 + q2;
                    if (Mi < lane) {
                        unsigned idxJ = ~(unsigned)keys[pos + Mi];
                        if (iou_f(s_allbox[idxJ], s_allarea[idxJ], bL, aL) > NMS_T)
                            bits |= (1ull << Mi);
                    }
                }
                if (bits) atomicOr(&s_supp[lane], bits);
            }
            __syncthreads();

            // D: wave0 resolves greedy recurrence by PEELING: keep the
            // minimum remaining candidate, remove all its victims with ONE
            // ballot of (own>>i)&1. Iterations = in-batch keeps.
            if (tid < 64) {
                unsigned long long own      = s_supp[lane];
                unsigned long long deadmask = __ballot(s_supc[lane] != 0);
                bool alive = (lane < bn) && !((deadmask >> lane) & 1ull);
                // lanes with no in-batch suppressors are kept immediately
                unsigned long long kept = __ballot(alive && own == 0ull);
                // one ballot removes every lane suppressed by an auto-kept lane
                unsigned long long rem0 = __ballot((own & kept) != 0ull);
                unsigned long long cand = __ballot(alive && own != 0ull) & ~rem0;
                while (cand) {
                    int i = __ffsll(cand) - 1;    // min remaining: always kept
                    kept |= 1ull << i;
                    unsigned long long vic = __ballot(((own >> i) & 1ull) != 0ull);
                    cand &= ~vic;
                    cand &= ~(1ull << i);
                }
                int keptN = (int)__popcll(kept);
                bool me   = (kept >> lane) & 1ull;
                int krank = (int)__popcll(kept & ((1ull << lane) - 1ull));
                if (me) {
                    int kid = cnt + krank;        // < MAXKEEP by construction
                    unsigned long long kk = keys[pos + lane];
                    unsigned idx = ~(unsigned)kk;
                    float4 bx = s_allbox[idx];
                    s_kb[kid] = bx;
                    s_ka[kid] = s_allarea[idx];
                    if (kid < TOPK) {
                        float* o = outbase + (size_t)kid * 5;
                        o[0] = __uint_as_float((unsigned)(kk >> 32));
                        o[1] = bx.x; o[2] = bx.y; o[3] = bx.z; o[4] = bx.w;
                    }
                }
                s_supp[lane] = 0ull;              // reset for next round
                s_supc[lane] = 0;
                if (lane == 0) {
                    s_cnt  = cnt + keptN;
                    s_done = (cnt + keptN >= TOPK) ? 1 : 0;
                }
            }
            __syncthreads();
            if (s_done) { done = true; break; }   // first TOPK rows fixed
            pos += bn;
        }

        if (done) break;
        if (T <= LO_BITS) break;                  // all candidates consumed
        Thi = T;                                  // next rung: scores in [?, T)
        // advance rung index past any boundary == T (bisect may have raised T)
        while (rung < 14 && LADDER[rung] >= T) rung++;
    }

    // ---- zero unwritten tail rows ----
    const int cf = s_cnt < TOPK ? s_cnt : TOPK;
    for (int r = cf + tid; r < TOPK; r += BLOCK) {
        float* o = outbase + (size_t)r * 5;
        o[0] = 0.f; o[1] = 0.f; o[2] = 0.f; o[3] = 0.f; o[4] = 0.f;
    }
}

extern "C" void kernel_launch(void* const* d_in, const int* in_sizes, int n_in,
                              void* d_out, int out_size, void* d_ws, size_t ws_size,
                              hipStream_t stream) {
    const float* loc    = (const float*)d_in[0];
    const float* conf   = (const float*)d_in[1];
    const float* priors = (const float*)d_in[2];
    float* out          = (float*)d_out;
    const int B = in_sizes[0] / (PNUM * 4);   // 8
    dim3 grid(NCLS, B);
    ssd_nms_kernel<<<grid, BLOCK, 0, stream>>>(loc, conf, priors, out);
}